// Round 1
// baseline (1562.383 us; speedup 1.0000x reference)
//
#include <hip/hip_runtime.h>
#include <hip/hip_bf16.h>
#include <math.h>

#define DIM 64

// ---------------- degree / normalization ----------------
__global__ __launch_bounds__(256) void k_deg(const int* __restrict__ col, int* __restrict__ deg, int E) {
  int i = blockIdx.x * 256 + threadIdx.x;
  if (i < E) atomicAdd(&deg[col[i]], 1);
}

__global__ __launch_bounds__(256) void k_dis(const int* __restrict__ deg, float* __restrict__ dis, int N) {
  int i = blockIdx.x * 256 + threadIdx.x;
  if (i < N) dis[i] = rsqrtf((float)(deg[i] + 1));  // +1 self-loop; always > 0
}

// ---------------- exclusive scan of in-degree counts (CSR offsets) ----------------
__global__ __launch_bounds__(256) void k_scan_a(const int* __restrict__ cnt, int* __restrict__ offs,
                                                int* __restrict__ bsums, int N) {
  __shared__ int ts[256];
  int t = threadIdx.x;
  int base = blockIdx.x * 2048 + t * 8;
  int v[8];
  int tot = 0;
#pragma unroll
  for (int j = 0; j < 8; ++j) {
    int idx = base + j;
    v[j] = (idx < N) ? cnt[idx] : 0;
    tot += v[j];
  }
  ts[t] = tot;
  __syncthreads();
  for (int d = 1; d < 256; d <<= 1) {
    int val = (t >= d) ? ts[t - d] : 0;
    __syncthreads();
    if (t >= d) ts[t] += val;
    __syncthreads();
  }
  int run = ts[t] - tot;  // exclusive prefix for this thread
#pragma unroll
  for (int j = 0; j < 8; ++j) {
    int idx = base + j;
    if (idx < N) offs[idx] = run;
    run += v[j];
  }
  if (t == 255) bsums[blockIdx.x] = ts[255];
}

__global__ void k_scan_b(int* bsums, int nb) {
  if (blockIdx.x == 0 && threadIdx.x == 0) {
    int run = 0;
    for (int i = 0; i < nb; ++i) { int v = bsums[i]; bsums[i] = run; run += v; }
  }
}

__global__ __launch_bounds__(256) void k_scan_c(int* __restrict__ offs, const int* __restrict__ bsums, int N) {
  int i = blockIdx.x * 256 + threadIdx.x;
  if (i < N) offs[i] += bsums[i >> 11];
}

// ---------------- CSR reorder (by target node) ----------------
__global__ __launch_bounds__(256) void k_reorder(const int* __restrict__ row, const int* __restrict__ col,
                                                 const int* __restrict__ offs, int* __restrict__ cursor,
                                                 const float* __restrict__ dis, int* __restrict__ src,
                                                 float* __restrict__ w, int E) {
  int e = blockIdx.x * 256 + threadIdx.x;
  if (e < E) {
    int r = row[e], c = col[e];
    int p = offs[c] + atomicAdd(&cursor[c], 1);
    src[p] = r;
    w[p] = dis[r] * dis[c];
  }
}

// ---------------- GEMM layer 1: xl = x @ W1 (raw input) ----------------
__global__ __launch_bounds__(256) void k_gemm_in(const float* __restrict__ x, const float* __restrict__ W,
                                                 float* __restrict__ xl, int N, int FIN) {
  __shared__ float Ws[128 * DIM];
  __shared__ float vbuf[4][128];
  int tid = threadIdx.x;
  for (int i = tid; i < FIN * DIM; i += 256) Ws[i] = W[i];
  __syncthreads();
  int wave = tid >> 6, lane = tid & 63;
  int stride = gridDim.x * 4;
  for (int n = blockIdx.x * 4 + wave; n < N; n += stride) {
    const float* xr = x + (size_t)n * FIN;
    for (int k = lane; k < FIN; k += 64) vbuf[wave][k] = xr[k];
    float acc = 0.f;
#pragma unroll 16
    for (int k = 0; k < FIN; ++k) acc = fmaf(vbuf[wave][k], Ws[k * DIM + lane], acc);
    xl[(size_t)n * DIM + lane] = acc;
  }
}

// ---------------- GEMM layers 2-4: xl = bn(y) @ W, bn fused from sums ----------------
__global__ __launch_bounds__(256) void k_gemm_bn(const float* __restrict__ y, const float* __restrict__ W,
                                                 const float* __restrict__ gam, const float* __restrict__ bet,
                                                 const float* __restrict__ s1, const float* __restrict__ s2,
                                                 float* __restrict__ xl, int N) {
  __shared__ float Ws[DIM * DIM];
  __shared__ float aL[DIM], cL[DIM];
  __shared__ float vbuf[4][DIM];
  int tid = threadIdx.x;
  for (int i = tid; i < DIM * DIM; i += 256) Ws[i] = W[i];
  if (tid < DIM) {
    float invN = 1.0f / (float)N;
    float m = s1[tid] * invN;
    float var = s2[tid] * invN - m * m;
    float inv = rsqrtf(var + 1e-5f);
    float a = gam[tid] * inv;
    aL[tid] = a;
    cL[tid] = fmaf(-m, a, bet[tid]);
  }
  __syncthreads();
  int wave = tid >> 6, lane = tid & 63;
  int stride = gridDim.x * 4;
  for (int n = blockIdx.x * 4 + wave; n < N; n += stride) {
    vbuf[wave][lane] = fmaf(aL[lane], y[(size_t)n * DIM + lane], cL[lane]);
    float acc = 0.f;
#pragma unroll
    for (int k = 0; k < DIM; ++k) acc = fmaf(vbuf[wave][k], Ws[k * DIM + lane], acc);
    xl[(size_t)n * DIM + lane] = acc;
  }
}

// ---------------- aggregation: y = relu(sum_edges + selfloop + b), BN sums fused ----------------
__global__ __launch_bounds__(256) void k_agg(const float* __restrict__ xl, const int* __restrict__ offs,
                                             const int* __restrict__ cnt, const int* __restrict__ src,
                                             const float* __restrict__ w, const float* __restrict__ dis,
                                             const float* __restrict__ bias, float* __restrict__ y,
                                             float* __restrict__ s1, float* __restrict__ s2, int N) {
  int tid = threadIdx.x;
  int wave = tid >> 6, lane = tid & 63;
  float ls = 0.f, lq = 0.f;
  float b = bias[lane];
  int stride = gridDim.x * 4;
  for (int n = blockIdx.x * 4 + wave; n < N; n += stride) {
    float di = dis[n];
    float acc = di * di * xl[(size_t)n * DIM + lane];  // self-loop
    int beg = offs[n];
    int end = beg + cnt[n];
    int p = beg;
    for (; p + 1 < end; p += 2) {
      int sa = src[p], sb = src[p + 1];
      float wa = w[p], wb = w[p + 1];
      float va = xl[(size_t)sa * DIM + lane];
      float vb = xl[(size_t)sb * DIM + lane];
      acc = fmaf(wa, va, acc);
      acc = fmaf(wb, vb, acc);
    }
    if (p < end) acc = fmaf(w[p], xl[(size_t)src[p] * DIM + lane], acc);
    float yv = fmaxf(acc + b, 0.f);
    y[(size_t)n * DIM + lane] = yv;
    ls += yv;
    lq = fmaf(yv, yv, lq);
  }
  __shared__ float rbuf[256];
  rbuf[tid] = ls;
  __syncthreads();
  if (tid < 64) atomicAdd(&s1[tid], rbuf[tid] + rbuf[tid + 64] + rbuf[tid + 128] + rbuf[tid + 192]);
  __syncthreads();
  rbuf[tid] = lq;
  __syncthreads();
  if (tid < 64) atomicAdd(&s2[tid], rbuf[tid] + rbuf[tid + 64] + rbuf[tid + 128] + rbuf[tid + 192]);
}

// ---------------- global mean pool (stage 1: sums) with BN4 fused ----------------
__global__ __launch_bounds__(256) void k_pool(const float* __restrict__ y, const float* __restrict__ gam,
                                              const float* __restrict__ bet, const float* __restrict__ s1,
                                              const float* __restrict__ s2, const int* __restrict__ batch,
                                              float* __restrict__ pooled, float* __restrict__ gcnt, int N) {
  __shared__ float aL[DIM], cL[DIM];
  int tid = threadIdx.x;
  if (tid < DIM) {
    float invN = 1.0f / (float)N;
    float m = s1[tid] * invN;
    float var = s2[tid] * invN - m * m;
    float inv = rsqrtf(var + 1e-5f);
    float a = gam[tid] * inv;
    aL[tid] = a;
    cL[tid] = fmaf(-m, a, bet[tid]);
  }
  __syncthreads();
  int wave = tid >> 6, lane = tid & 63;
  int stride = gridDim.x * 4;
  for (int n = blockIdx.x * 4 + wave; n < N; n += stride) {
    int gi = batch[n];
    float v = fmaf(aL[lane], y[(size_t)n * DIM + lane], cL[lane]);
    atomicAdd(&pooled[(size_t)gi * DIM + lane], v);
    if (lane == 0) atomicAdd(&gcnt[gi], 1.f);
  }
}

// ---------------- head: mean, fc, log_softmax ----------------
__global__ __launch_bounds__(256) void k_head(const float* __restrict__ pooled, const float* __restrict__ gcnt,
                                              const float* __restrict__ fcW, const float* __restrict__ fcb,
                                              float* __restrict__ out, int G, int C) {
  int g = blockIdx.x * 256 + threadIdx.x;
  if (g >= G) return;
  float z[16];
  for (int c = 0; c < C; ++c) z[c] = fcb[c];
  float inv = 1.f / fmaxf(gcnt[g], 1.f);
  for (int f = 0; f < DIM; ++f) {
    float p = pooled[(size_t)g * DIM + f] * inv;
    for (int c = 0; c < C; ++c) z[c] = fmaf(p, fcW[f * C + c], z[c]);
  }
  float m = -1e30f;
  for (int c = 0; c < C; ++c) m = fmaxf(m, z[c]);
  float s = 0.f;
  for (int c = 0; c < C; ++c) s += expf(z[c] - m);
  float ls = logf(s);
  for (int c = 0; c < C; ++c) out[(size_t)g * C + c] = z[c] - m - ls;
}

extern "C" void kernel_launch(void* const* d_in, const int* in_sizes, int n_in,
                              void* d_out, int out_size, void* d_ws, size_t ws_size,
                              hipStream_t stream) {
  const float* x    = (const float*)d_in[0];
  const int*   ei   = (const int*)d_in[1];
  const int*   batch= (const int*)d_in[2];
  const float* W1 = (const float*)d_in[4];
  const float* b1 = (const float*)d_in[5];
  const float* W2 = (const float*)d_in[6];
  const float* b2 = (const float*)d_in[7];
  const float* W3 = (const float*)d_in[8];
  const float* b3 = (const float*)d_in[9];
  const float* W4 = (const float*)d_in[10];
  const float* b4 = (const float*)d_in[11];
  const float* g1 = (const float*)d_in[12];
  const float* be1= (const float*)d_in[13];
  const float* g2 = (const float*)d_in[14];
  const float* be2= (const float*)d_in[15];
  const float* g3 = (const float*)d_in[16];
  const float* be3= (const float*)d_in[17];
  const float* g4 = (const float*)d_in[18];
  const float* be4= (const float*)d_in[19];
  const float* fcW= (const float*)d_in[20];
  const float* fcb= (const float*)d_in[21];
  float* out = (float*)d_out;

  int N   = in_sizes[2];
  int E   = in_sizes[1] / 2;
  int FIN = in_sizes[4] / DIM;
  int C   = in_sizes[21];
  int G   = out_size / C;

  char* ws = (char*)d_ws;
  size_t off = 0;
  auto alloc = [&](size_t bytes) { size_t o = off; off = (off + bytes + 255) & ~(size_t)255; return o; };
  size_t o_deg  = alloc((size_t)N * 4);
  size_t o_cur  = alloc((size_t)N * 4);
  size_t o_bn   = alloc(4 * 2 * 64 * 4);
  size_t o_pool = alloc((size_t)G * DIM * 4);
  size_t o_gcnt = alloc((size_t)G * 4);
  size_t zero_bytes = off;            // everything above must start at 0
  size_t o_dis  = alloc((size_t)N * 4);
  size_t o_offs = alloc((size_t)N * 4);
  size_t o_bs   = alloc(256 * 4);
  size_t o_src  = alloc((size_t)E * 4);
  size_t o_w    = alloc((size_t)E * 4);
  size_t o_xl   = alloc((size_t)N * DIM * 4);
  size_t o_y    = alloc((size_t)N * DIM * 4);
  (void)ws_size;

  int*   deg    = (int*)(ws + o_deg);
  int*   cur    = (int*)(ws + o_cur);
  float* bn     = (float*)(ws + o_bn);
  float* pooled = (float*)(ws + o_pool);
  float* gcnt   = (float*)(ws + o_gcnt);
  float* dis    = (float*)(ws + o_dis);
  int*   offs   = (int*)(ws + o_offs);
  int*   bs     = (int*)(ws + o_bs);
  int*   csrs   = (int*)(ws + o_src);
  float* csrw   = (float*)(ws + o_w);
  float* xl     = (float*)(ws + o_xl);
  float* y      = (float*)(ws + o_y);

  hipMemsetAsync(d_ws, 0, zero_bytes, stream);

  const int* row  = ei;
  const int* colp = ei + E;
  int ebl = (E + 255) / 256;
  int nbl = (N + 255) / 256;
  int nb  = (N + 2047) / 2048;

  k_deg<<<ebl, 256, 0, stream>>>(colp, deg, E);
  k_dis<<<nbl, 256, 0, stream>>>(deg, dis, N);
  k_scan_a<<<nb, 256, 0, stream>>>(deg, offs, bs, N);
  k_scan_b<<<1, 64, 0, stream>>>(bs, nb);
  k_scan_c<<<nbl, 256, 0, stream>>>(offs, bs, N);
  k_reorder<<<ebl, 256, 0, stream>>>(row, colp, offs, cur, dis, csrs, csrw, E);

  // Layer 1
  k_gemm_in<<<1024, 256, 0, stream>>>(x, W1, xl, N, FIN);
  k_agg<<<2048, 256, 0, stream>>>(xl, offs, deg, csrs, csrw, dis, b1, y, bn + 0, bn + 64, N);
  // Layer 2 (applies BN1 on the fly)
  k_gemm_bn<<<2048, 256, 0, stream>>>(y, W2, g1, be1, bn + 0, bn + 64, xl, N);
  k_agg<<<2048, 256, 0, stream>>>(xl, offs, deg, csrs, csrw, dis, b2, y, bn + 128, bn + 192, N);
  // Layer 3
  k_gemm_bn<<<2048, 256, 0, stream>>>(y, W3, g2, be2, bn + 128, bn + 192, xl, N);
  k_agg<<<2048, 256, 0, stream>>>(xl, offs, deg, csrs, csrw, dis, b3, y, bn + 256, bn + 320, N);
  // Layer 4
  k_gemm_bn<<<2048, 256, 0, stream>>>(y, W4, g3, be3, bn + 256, bn + 320, xl, N);
  k_agg<<<2048, 256, 0, stream>>>(xl, offs, deg, csrs, csrw, dis, b4, y, bn + 384, bn + 448, N);
  // Pool (applies BN4) + head
  k_pool<<<2048, 256, 0, stream>>>(y, g4, be4, bn + 384, bn + 448, batch, pooled, gcnt, N);
  k_head<<<(G + 255) / 256, 256, 0, stream>>>(pooled, gcnt, fcW, fcb, out, G, C);
}

// Round 3
// 1346.370 us; speedup vs baseline: 1.1604x; 1.1604x over previous
//
#include <hip/hip_runtime.h>
#include <hip/hip_bf16.h>
#include <math.h>

#define DIM 64
typedef _Float16 f16;

// ---------------- degree / normalization ----------------
__global__ __launch_bounds__(256) void k_deg(const int* __restrict__ col, int* __restrict__ deg, int E) {
  int i = blockIdx.x * 256 + threadIdx.x;
  if (i < E) atomicAdd(&deg[col[i]], 1);
}

__global__ __launch_bounds__(256) void k_dis(const int* __restrict__ deg, float* __restrict__ dis, int N) {
  int i = blockIdx.x * 256 + threadIdx.x;
  if (i < N) dis[i] = rsqrtf((float)(deg[i] + 1));  // +1 self-loop; always > 0
}

// ---------------- exclusive scan of in-degree counts (CSR offsets) ----------------
__global__ __launch_bounds__(256) void k_scan_a(const int* __restrict__ cnt, int* __restrict__ offs,
                                                int* __restrict__ bsums, int N) {
  __shared__ int ts[256];
  int t = threadIdx.x;
  int base = blockIdx.x * 2048 + t * 8;
  int v[8];
  int tot = 0;
#pragma unroll
  for (int j = 0; j < 8; ++j) {
    int idx = base + j;
    v[j] = (idx < N) ? cnt[idx] : 0;
    tot += v[j];
  }
  ts[t] = tot;
  __syncthreads();
  for (int d = 1; d < 256; d <<= 1) {
    int val = (t >= d) ? ts[t - d] : 0;
    __syncthreads();
    if (t >= d) ts[t] += val;
    __syncthreads();
  }
  int run = ts[t] - tot;
#pragma unroll
  for (int j = 0; j < 8; ++j) {
    int idx = base + j;
    if (idx < N) offs[idx] = run;
    run += v[j];
  }
  if (t == 255) bsums[blockIdx.x] = ts[255];
}

__global__ void k_scan_b(int* bsums, int nb) {
  if (blockIdx.x == 0 && threadIdx.x == 0) {
    int run = 0;
    for (int i = 0; i < nb; ++i) { int v = bsums[i]; bsums[i] = run; run += v; }
  }
}

__global__ __launch_bounds__(256) void k_scan_c(int* __restrict__ offs, const int* __restrict__ bsums, int N) {
  int i = blockIdx.x * 256 + threadIdx.x;
  if (i < N) offs[i] += bsums[i >> 11];
}

// ---------------- CSR reorder (by target node); only src stored ----------------
__global__ __launch_bounds__(256) void k_reorder(const int* __restrict__ row, const int* __restrict__ col,
                                                 const int* __restrict__ offs, int* __restrict__ cursor,
                                                 int* __restrict__ src, int E) {
  int e = blockIdx.x * 256 + threadIdx.x;
  if (e < E) {
    int c = col[e];
    int p = offs[c] + atomicAdd(&cursor[c], 1);
    src[p] = row[e];
  }
}

// ---------------- GEMM layer 1: xl2 = dis * (x @ W1), fp16 out ----------------
__global__ __launch_bounds__(256) void k_gemm_in(const float* __restrict__ x, const float* __restrict__ W,
                                                 const float* __restrict__ dis, f16* __restrict__ xl,
                                                 int N, int FIN) {
  __shared__ float Ws[128 * DIM];
  __shared__ float vbuf[4][128];
  int tid = threadIdx.x;
  for (int i = tid; i < FIN * DIM; i += 256) Ws[i] = W[i];
  __syncthreads();
  int wave = tid >> 6, lane = tid & 63;
  int stride = gridDim.x * 4;
  for (int n = blockIdx.x * 4 + wave; n < N; n += stride) {
    const float* xr = x + (size_t)n * FIN;
    for (int k = lane; k < FIN; k += 64) vbuf[wave][k] = xr[k];
    float acc = 0.f;
#pragma unroll 16
    for (int k = 0; k < FIN; ++k) acc = fmaf(vbuf[wave][k], Ws[k * DIM + lane], acc);
    xl[(size_t)n * DIM + lane] = (f16)(acc * dis[n]);
  }
}

// ---------------- GEMM layers 2-4: xl2 = dis * (bn(y) @ W), fp16 out ----------------
__global__ __launch_bounds__(256) void k_gemm_bn(const float* __restrict__ y, const float* __restrict__ W,
                                                 const float* __restrict__ gam, const float* __restrict__ bet,
                                                 const float* __restrict__ s1, const float* __restrict__ s2,
                                                 const float* __restrict__ dis, f16* __restrict__ xl, int N) {
  __shared__ float Ws[DIM * DIM];
  __shared__ float aL[DIM], cL[DIM];
  __shared__ float vbuf[4][DIM];
  int tid = threadIdx.x;
  for (int i = tid; i < DIM * DIM; i += 256) Ws[i] = W[i];
  if (tid < DIM) {
    float invN = 1.0f / (float)N;
    float m = s1[tid] * invN;
    float var = s2[tid] * invN - m * m;
    float inv = rsqrtf(var + 1e-5f);
    float a = gam[tid] * inv;
    aL[tid] = a;
    cL[tid] = fmaf(-m, a, bet[tid]);
  }
  __syncthreads();
  int wave = tid >> 6, lane = tid & 63;
  int stride = gridDim.x * 4;
  for (int n = blockIdx.x * 4 + wave; n < N; n += stride) {
    vbuf[wave][lane] = fmaf(aL[lane], y[(size_t)n * DIM + lane], cL[lane]);
    float acc = 0.f;
#pragma unroll
    for (int k = 0; k < DIM; ++k) acc = fmaf(vbuf[wave][k], Ws[k * DIM + lane], acc);
    xl[(size_t)n * DIM + lane] = (f16)(acc * dis[n]);
  }
}

// ---------------- aggregation: y = relu(dis[n]*(sum xl2[src] + xl2[n]) + b), BN sums fused ----------------
__global__ __launch_bounds__(256) void k_agg(const f16* __restrict__ xl, const int* __restrict__ offs,
                                             const int* __restrict__ cnt, const int* __restrict__ src,
                                             const float* __restrict__ dis, const float* __restrict__ bias,
                                             float* __restrict__ y, float* __restrict__ s1,
                                             float* __restrict__ s2, int N) {
  int tid = threadIdx.x;
  int wave = tid >> 6, lane = tid & 63;
  float ls = 0.f, lq = 0.f;
  float b = bias[lane];
  int stride = gridDim.x * 4;
  for (int n = blockIdx.x * 4 + wave; n < N; n += stride) {
    float di = dis[n];
    float acc = (float)xl[(size_t)n * DIM + lane];  // self-loop term (already dis-scaled)
    int beg = offs[n];
    int end = beg + cnt[n];
    int p = beg;
    for (; p + 3 < end; p += 4) {
      int s0 = src[p], s1i = src[p + 1], s2i = src[p + 2], s3i = src[p + 3];
      float v0 = (float)xl[(size_t)s0 * DIM + lane];
      float v1 = (float)xl[(size_t)s1i * DIM + lane];
      float v2 = (float)xl[(size_t)s2i * DIM + lane];
      float v3 = (float)xl[(size_t)s3i * DIM + lane];
      acc += (v0 + v1) + (v2 + v3);
    }
    for (; p < end; ++p) acc += (float)xl[(size_t)src[p] * DIM + lane];
    float yv = fmaxf(fmaf(di, acc, b), 0.f);
    y[(size_t)n * DIM + lane] = yv;
    ls += yv;
    lq = fmaf(yv, yv, lq);
  }
  __shared__ float rbuf[256];
  rbuf[tid] = ls;
  __syncthreads();
  if (tid < 64) atomicAdd(&s1[tid], rbuf[tid] + rbuf[tid + 64] + rbuf[tid + 128] + rbuf[tid + 192]);
  __syncthreads();
  rbuf[tid] = lq;
  __syncthreads();
  if (tid < 64) atomicAdd(&s2[tid], rbuf[tid] + rbuf[tid + 64] + rbuf[tid + 128] + rbuf[tid + 192]);
}

// ---------------- global mean pool: segmented (batch sorted), BN4 fused ----------------
__global__ __launch_bounds__(256) void k_pool(const float* __restrict__ y, const float* __restrict__ gam,
                                              const float* __restrict__ bet, const float* __restrict__ s1,
                                              const float* __restrict__ s2, const int* __restrict__ batch,
                                              float* __restrict__ pooled, float* __restrict__ gcnt,
                                              int N, int chunk) {
  __shared__ float aL[DIM], cL[DIM];
  int tid = threadIdx.x;
  if (tid < DIM) {
    float invN = 1.0f / (float)N;
    float m = s1[tid] * invN;
    float var = s2[tid] * invN - m * m;
    float inv = rsqrtf(var + 1e-5f);
    float a = gam[tid] * inv;
    aL[tid] = a;
    cL[tid] = fmaf(-m, a, bet[tid]);
  }
  __syncthreads();
  int wave = tid >> 6, lane = tid & 63;
  int wid = blockIdx.x * 4 + wave;
  int n0 = wid * chunk;
  int n1 = min(N, n0 + chunk);
  if (n0 >= N) return;
  int cur_g = batch[n0];
  float acc = 0.f;
  int cntn = 0;
  for (int n = n0; n < n1; ++n) {
    int gi = batch[n];
    if (gi != cur_g) {
      atomicAdd(&pooled[(size_t)cur_g * DIM + lane], acc);
      if (lane == 0) atomicAdd(&gcnt[cur_g], (float)cntn);
      cur_g = gi; acc = 0.f; cntn = 0;
    }
    acc += fmaf(aL[lane], y[(size_t)n * DIM + lane], cL[lane]);
    ++cntn;
  }
  atomicAdd(&pooled[(size_t)cur_g * DIM + lane], acc);
  if (lane == 0) atomicAdd(&gcnt[cur_g], (float)cntn);
}

// ---------------- head: mean, fc, log_softmax ----------------
__global__ __launch_bounds__(256) void k_head(const float* __restrict__ pooled, const float* __restrict__ gcnt,
                                              const float* __restrict__ fcW, const float* __restrict__ fcb,
                                              float* __restrict__ out, int G, int C) {
  int g = blockIdx.x * 256 + threadIdx.x;
  if (g >= G) return;
  float z[16];
  for (int c = 0; c < C; ++c) z[c] = fcb[c];
  float inv = 1.f / fmaxf(gcnt[g], 1.f);
  for (int f = 0; f < DIM; ++f) {
    float p = pooled[(size_t)g * DIM + f] * inv;
    for (int c = 0; c < C; ++c) z[c] = fmaf(p, fcW[f * C + c], z[c]);
  }
  float m = -1e30f;
  for (int c = 0; c < C; ++c) m = fmaxf(m, z[c]);
  float s = 0.f;
  for (int c = 0; c < C; ++c) s += expf(z[c] - m);
  float ls = logf(s);
  for (int c = 0; c < C; ++c) out[(size_t)g * C + c] = z[c] - m - ls;
}

extern "C" void kernel_launch(void* const* d_in, const int* in_sizes, int n_in,
                              void* d_out, int out_size, void* d_ws, size_t ws_size,
                              hipStream_t stream) {
  const float* x    = (const float*)d_in[0];
  const int*   ei   = (const int*)d_in[1];
  const int*   batch= (const int*)d_in[2];
  const float* W1 = (const float*)d_in[4];
  const float* b1 = (const float*)d_in[5];
  const float* W2 = (const float*)d_in[6];
  const float* b2 = (const float*)d_in[7];
  const float* W3 = (const float*)d_in[8];
  const float* b3 = (const float*)d_in[9];
  const float* W4 = (const float*)d_in[10];
  const float* b4 = (const float*)d_in[11];
  const float* g1 = (const float*)d_in[12];
  const float* be1= (const float*)d_in[13];
  const float* g2 = (const float*)d_in[14];
  const float* be2= (const float*)d_in[15];
  const float* g3 = (const float*)d_in[16];
  const float* be3= (const float*)d_in[17];
  const float* g4 = (const float*)d_in[18];
  const float* be4= (const float*)d_in[19];
  const float* fcW= (const float*)d_in[20];
  const float* fcb= (const float*)d_in[21];
  float* out = (float*)d_out;

  int N   = in_sizes[2];
  int E   = in_sizes[1] / 2;
  int FIN = in_sizes[4] / DIM;
  int C   = in_sizes[21];
  int G   = out_size / C;

  char* ws = (char*)d_ws;
  size_t off = 0;
  auto alloc = [&](size_t bytes) { size_t o = off; off = (off + bytes + 255) & ~(size_t)255; return o; };
  size_t o_deg  = alloc((size_t)N * 4);
  size_t o_cur  = alloc((size_t)N * 4);
  size_t o_bn   = alloc(4 * 2 * 64 * 4);
  size_t o_pool = alloc((size_t)G * DIM * 4);
  size_t o_gcnt = alloc((size_t)G * 4);
  size_t zero_bytes = off;            // everything above must start at 0
  size_t o_dis  = alloc((size_t)N * 4);
  size_t o_offs = alloc((size_t)N * 4);
  size_t o_bs   = alloc(256 * 4);
  size_t o_src  = alloc((size_t)E * 4);
  size_t o_xl   = alloc((size_t)N * DIM * 2);   // fp16
  size_t o_y    = alloc((size_t)N * DIM * 4);
  (void)ws_size;

  int*   deg    = (int*)(ws + o_deg);
  int*   cur    = (int*)(ws + o_cur);
  float* bn     = (float*)(ws + o_bn);
  float* pooled = (float*)(ws + o_pool);
  float* gcnt   = (float*)(ws + o_gcnt);
  float* dis    = (float*)(ws + o_dis);
  int*   offs   = (int*)(ws + o_offs);
  int*   bs     = (int*)(ws + o_bs);
  int*   csrs   = (int*)(ws + o_src);
  f16*   xl     = (f16*)(ws + o_xl);
  float* y      = (float*)(ws + o_y);

  hipMemsetAsync(d_ws, 0, zero_bytes, stream);

  const int* row  = ei;
  const int* colp = ei + E;
  int ebl = (E + 255) / 256;
  int nbl = (N + 255) / 256;
  int nb  = (N + 2047) / 2048;

  k_deg<<<ebl, 256, 0, stream>>>(colp, deg, E);
  k_dis<<<nbl, 256, 0, stream>>>(deg, dis, N);
  k_scan_a<<<nb, 256, 0, stream>>>(deg, offs, bs, N);
  k_scan_b<<<1, 64, 0, stream>>>(bs, nb);
  k_scan_c<<<nbl, 256, 0, stream>>>(offs, bs, N);
  k_reorder<<<ebl, 256, 0, stream>>>(row, colp, offs, cur, csrs, E);

  // Layer 1
  k_gemm_in<<<1024, 256, 0, stream>>>(x, W1, dis, xl, N, FIN);
  k_agg<<<2048, 256, 0, stream>>>(xl, offs, deg, csrs, dis, b1, y, bn + 0, bn + 64, N);
  // Layer 2 (applies BN1 on the fly)
  k_gemm_bn<<<2048, 256, 0, stream>>>(y, W2, g1, be1, bn + 0, bn + 64, dis, xl, N);
  k_agg<<<2048, 256, 0, stream>>>(xl, offs, deg, csrs, dis, b2, y, bn + 128, bn + 192, N);
  // Layer 3
  k_gemm_bn<<<2048, 256, 0, stream>>>(y, W3, g2, be2, bn + 128, bn + 192, dis, xl, N);
  k_agg<<<2048, 256, 0, stream>>>(xl, offs, deg, csrs, dis, b3, y, bn + 256, bn + 320, N);
  // Layer 4
  k_gemm_bn<<<2048, 256, 0, stream>>>(y, W4, g3, be3, bn + 256, bn + 320, dis, xl, N);
  k_agg<<<2048, 256, 0, stream>>>(xl, offs, deg, csrs, dis, b4, y, bn + 384, bn + 448, N);
  // Pool (applies BN4) + head
  int nwaves = 2048;
  int chunk = (N + nwaves - 1) / nwaves;
  k_pool<<<nwaves / 4, 256, 0, stream>>>(y, g4, be4, bn + 384, bn + 448, batch, pooled, gcnt, N, chunk);
  k_head<<<(G + 255) / 256, 256, 0, stream>>>(pooled, gcnt, fcW, fcb, out, G, C);
}